// Round 1
// baseline (469.790 us; speedup 1.0000x reference)
//
#include <hip/hip_runtime.h>
#include <cstdint>
#include <cstddef>

// CPDLoss (SSD MultiBox-style): B=8 batches, A=131072 anchors, M=64 truths.
// Pipeline: memset(ws) -> prep -> match -> override -> main -> sel2 -> sel3 -> final.
// Hard-negative mining done as exact 3-level radix select (11/11/10 bits) on the
// CE float bit patterns (monotone uint for positive floats), with per-bin
// counts + double sums; top-k SUM is tie-invariant so this matches the
// argsort-based reference exactly.

#define A_N 131072
#define B_N 8
#define M_N 64
#define OVTH 0.5f
#define VAR0 0.1f

// ---------------------------------------------------------------- prep targets
__global__ void k_prep(const float* __restrict__ targets,
                       float4* __restrict__ tbox, float2* __restrict__ tav)
{
  int i = blockIdx.x * blockDim.x + threadIdx.x;
  if (i >= B_N * M_N) return;
  const float* t = targets + (size_t)i * 5;
  float x1 = t[0], y1 = t[1], x2 = t[2], y2 = t[3], lab = t[4];
  tbox[i] = make_float4(x1, y1, x2, y2);
  tav[i]  = make_float2((x2 - x1) * (y2 - y1), lab > 0.f ? 1.f : 0.f);
}

// ---------------------------------------------------------------- match kernel
// thread = one anchor (8 per thread over iterations); inner loop over 64 truths.
// best_truth: thread-local strict-> (first-max == jnp.argmax).
// best_prior: per-m wave butterfly + per-block LDS + packed u64 atomicMax
//             (key = iou_bits<<32 | (0x1FFFFFFF - a): tie -> smallest anchor).
__launch_bounds__(256)
__global__ void k_match(const float4* __restrict__ anchors,
                        const float4* __restrict__ tbox,
                        const float2* __restrict__ tav,
                        float* __restrict__ bestOv,
                        int* __restrict__ bestIdx,
                        unsigned long long* __restrict__ bpi)
{
  __shared__ float sVal[M_N][4];
  __shared__ int   sIdx[M_N][4];
  const int tid = threadIdx.x;
  const int wave = tid >> 6, lane = tid & 63;
  sVal[tid >> 2][tid & 3] = -2.0f;
  sIdx[tid >> 2][tid & 3] = 0x7FFFFFFF;
  __syncthreads();
  const int b = blockIdx.y;
  const float4* tb = tbox + b * M_N;
  const float2* ta = tav + b * M_N;
  const int base = blockIdx.x * 2048;
  for (int it = 0; it < 8; ++it) {
    const int a = base + it * 256 + tid;
    float4 an = anchors[a];
    float ax1 = an.x - an.z * 0.5f, ay1 = an.y - an.w * 0.5f;
    float ax2 = an.x + an.z * 0.5f, ay2 = an.y + an.w * 0.5f;
    float areaA = (ax2 - ax1) * (ay2 - ay1);
    float bv = -2.0f; int bm = 0;
    for (int m = 0; m < M_N; ++m) {
      float4 t = tb[m];
      float2 av = ta[m];
      float wx = fminf(ax2, t.z) - fmaxf(ax1, t.x);
      float wy = fminf(ay2, t.w) - fmaxf(ay1, t.y);
      wx = fmaxf(wx, 0.f); wy = fmaxf(wy, 0.f);
      float inter = wx * wy;
      float uni = areaA + av.x - inter;
      float q = inter / uni;                    // exact IEEE div: matches np ordering
      float val = (av.y > 0.f) ? q : -1.0f;     // masked overlap (invalid truth -> -1)
      if (val > bv) { bv = val; bm = m; }       // strict >: first-max
      float rv = val; int ri = a;
      #pragma unroll
      for (int off = 32; off; off >>= 1) {
        float ov2 = __shfl_xor(rv, off);
        int   oi2 = __shfl_xor(ri, off);
        bool better = (ov2 > rv) || (ov2 == rv && oi2 < ri);
        rv = better ? ov2 : rv;
        ri = better ? oi2 : ri;
      }
      if (lane == 0) {
        float cv = sVal[m][wave]; int ci = sIdx[m][wave];
        if (rv > cv || (rv == cv && ri < ci)) { sVal[m][wave] = rv; sIdx[m][wave] = ri; }
      }
    }
    bestOv[(size_t)b * A_N + a] = bv;
    bestIdx[(size_t)b * A_N + a] = bm;
  }
  __syncthreads();
  if (tid < M_N) {
    float v = sVal[tid][0]; int i0 = sIdx[tid][0];
    #pragma unroll
    for (int w = 1; w < 4; ++w) {
      float v2 = sVal[tid][w]; int i2 = sIdx[tid][w];
      if (v2 > v || (v2 == v && i2 < i0)) { v = v2; i0 = i2; }
    }
    unsigned long long key =
        ((unsigned long long)__float_as_uint(v) << 32) |
        (unsigned long long)(0x1FFFFFFFu - (unsigned)i0);
    atomicMax(bpi + b * M_N + tid, key);
  }
}

// ------------------------------------------------------------- forced override
// numpy scatter semantics: sequential ascending m, last write wins.
__global__ void k_override(const float2* __restrict__ tav,
                           const unsigned long long* __restrict__ bpi,
                           float* __restrict__ bestOv,
                           int* __restrict__ bestIdx)
{
  int b = threadIdx.x;
  if (b >= B_N) return;
  for (int m = 0; m < M_N; ++m) {
    if (tav[b * M_N + m].y > 0.f) {
      unsigned long long key = bpi[b * M_N + m];
      unsigned int a = 0x1FFFFFFFu - (unsigned int)(key & 0xFFFFFFFFull);
      bestOv[(size_t)b * A_N + a] = 2.0f;
      bestIdx[(size_t)b * A_N + a] = m;
    }
  }
}

// ------------------------------------------------------------------- main pass
__launch_bounds__(256)
__global__ void k_main(const float2* __restrict__ loc_pred,
                       const float2* __restrict__ conf_pred,
                       const float4* __restrict__ anchors,
                       const float4* __restrict__ tbox,
                       const float2* __restrict__ tav,
                       const float* __restrict__ bestOv,
                       const int* __restrict__ bestIdx,
                       unsigned int* __restrict__ ceBits,
                       unsigned int* __restrict__ h1cnt,
                       double* __restrict__ h1sum,
                       double* __restrict__ lossL,
                       double* __restrict__ lossCpos,
                       unsigned int* __restrict__ numpos)
{
  __shared__ unsigned int hc[2048];
  __shared__ float hs[2048];
  __shared__ double rL[4], rC[4];
  __shared__ unsigned int rN[4];
  const int tid = threadIdx.x;
  for (int j = tid; j < 2048; j += 256) { hc[j] = 0u; hs[j] = 0.f; }
  __syncthreads();
  const int b = blockIdx.y;
  const size_t gbase = (size_t)b * A_N + (size_t)blockIdx.x * 4096;
  double lL = 0.0, lC = 0.0;
  unsigned int npc = 0;
  for (int i = 0; i < 16; ++i) {
    const size_t g = gbase + i * 256 + tid;
    const int a = (int)(g - (size_t)b * A_N);
    float ov = bestOv[g];
    int idx = bestIdx[g];
    float2 av = tav[b * M_N + idx];
    int conf = (ov < OVTH) ? 0 : (av.y > 0.f ? 1 : 0);
    float2 cp = conf_pred[g];
    float mx = fmaxf(cp.x, cp.y), mn = fminf(cp.x, cp.y);
    float ce = (mx + log1pf(expf(mn - mx))) - (conf ? cp.y : cp.x);
    unsigned int bits = 0u;
    float hval = 0.f;
    if (conf) {
      npc++; lC += (double)ce;
      float4 t = tbox[b * M_N + idx];
      float4 an = anchors[a];
      float gx = ((t.x + t.z) * 0.5f - an.x) / (VAR0 * an.z);
      float gy = ((t.y + t.w) * 0.5f - an.y) / (VAR0 * an.w);
      float2 lp = loc_pred[g];
      float dx = fabsf(lp.x - gx), dy = fabsf(lp.y - gy);
      lL += (double)((dx < 1.f ? 0.5f * dx * dx : dx - 0.5f) +
                     (dy < 1.f ? 0.5f * dy * dy : dy - 0.5f));
    } else {
      bits = __float_as_uint(ce);   // ce > 0 -> monotone bits
      hval = ce;
    }
    ceBits[g] = bits;
    atomicAdd(&hc[bits >> 21], 1u);
    atomicAdd(&hs[bits >> 21], hval);
  }
  __syncthreads();
  for (int j = tid; j < 2048; j += 256) {
    unsigned int c = hc[j];
    if (c) {
      atomicAdd(h1cnt + b * 2048 + j, c);
      atomicAdd(h1sum + b * 2048 + j, (double)hs[j]);
    }
  }
  const int lane = tid & 63, wave = tid >> 6;
  for (int off = 32; off; off >>= 1) {
    lL += __shfl_down(lL, off);
    lC += __shfl_down(lC, off);
    npc += __shfl_down(npc, off);
  }
  if (lane == 0) { rL[wave] = lL; rC[wave] = lC; rN[wave] = npc; }
  __syncthreads();
  if (tid == 0) {
    double aL = 0, aC = 0; unsigned int n = 0;
    for (int w = 0; w < 4; ++w) { aL += rL[w]; aC += rC[w]; n += rN[w]; }
    if (aL != 0.0) atomicAdd(lossL, aL);
    if (aC != 0.0) atomicAdd(lossCpos, aC);
    if (n) atomicAdd(numpos + b, n);
  }
}

// ------------------------------------------------- radix-select helper (block)
// Finds bin t containing the k-th largest; outAb = count of entries in bins > t.
template <int PER>
__device__ void findBin(const unsigned int* __restrict__ h, unsigned int k,
                        unsigned int* scanBuf, int* outT, unsigned int* outAb)
{
  const int tid = threadIdx.x;
  unsigned int c[PER];
  unsigned int ps = 0;
  #pragma unroll
  for (int j = 0; j < PER; ++j) { c[j] = h[tid * PER + j]; ps += c[j]; }
  scanBuf[tid] = ps;
  __syncthreads();
  unsigned int v = ps;
  for (int off = 1; off < 256; off <<= 1) {
    unsigned int u = (tid + off < 256) ? scanBuf[tid + off] : 0u;
    __syncthreads();
    v += u;
    scanBuf[tid] = v;
    __syncthreads();
  }
  unsigned int above = v - ps;  // entries in chunks strictly above this thread's
  #pragma unroll
  for (int j = PER - 1; j >= 0; --j) {
    unsigned int cj = c[j];
    if (above < k && above + cj >= k) { *outT = tid * PER + j; *outAb = above; }
    above += cj;
  }
  __syncthreads();
}

// ----------------------------------------------------------- level-2 histogram
__launch_bounds__(256)
__global__ void k_sel2(const unsigned int* __restrict__ ceBits,
                       const unsigned int* __restrict__ h1cnt,
                       unsigned int* __restrict__ h2cnt,
                       double* __restrict__ h2sum,
                       const unsigned int* __restrict__ numpos)
{
  __shared__ unsigned int scanBuf[256];
  __shared__ int sT; __shared__ unsigned int sAb;
  __shared__ unsigned int h2c[2048];
  __shared__ float h2s[2048];
  const int b = blockIdx.y;
  const unsigned int P = numpos[b];
  const unsigned int k = min(3u * P, (unsigned)A_N - P);
  if (k == 0u) return;
  const int tid = threadIdx.x;
  findBin<8>(h1cnt + b * 2048, k, scanBuf, &sT, &sAb);
  const int t1 = sT;
  for (int j = tid; j < 2048; j += 256) { h2c[j] = 0u; h2s[j] = 0.f; }
  __syncthreads();
  const size_t base = (size_t)b * A_N + (size_t)blockIdx.x * 4096;
  for (int i = 0; i < 16; ++i) {
    unsigned int bits = ceBits[base + i * 256 + tid];
    if ((int)(bits >> 21) == t1) {
      int bin = (bits >> 10) & 2047;
      atomicAdd(&h2c[bin], 1u);
      atomicAdd(&h2s[bin], __uint_as_float(bits));
    }
  }
  __syncthreads();
  for (int j = tid; j < 2048; j += 256) {
    unsigned int cc = h2c[j];
    if (cc) {
      atomicAdd(h2cnt + b * 2048 + j, cc);
      atomicAdd(h2sum + b * 2048 + j, (double)h2s[j]);
    }
  }
}

// ----------------------------------------------------------- level-3 histogram
__launch_bounds__(256)
__global__ void k_sel3(const unsigned int* __restrict__ ceBits,
                       const unsigned int* __restrict__ h1cnt,
                       const unsigned int* __restrict__ h2cnt,
                       unsigned int* __restrict__ h3cnt,
                       const unsigned int* __restrict__ numpos)
{
  __shared__ unsigned int scanBuf[256];
  __shared__ int sT; __shared__ unsigned int sAb;
  __shared__ unsigned int h3c[1024];
  const int b = blockIdx.y;
  const unsigned int P = numpos[b];
  const unsigned int k = min(3u * P, (unsigned)A_N - P);
  if (k == 0u) return;
  const int tid = threadIdx.x;
  findBin<8>(h1cnt + b * 2048, k, scanBuf, &sT, &sAb);
  const int t1 = sT; const unsigned int k1 = k - sAb;
  findBin<8>(h2cnt + b * 2048, k1, scanBuf, &sT, &sAb);
  const int t2 = sT;
  const unsigned int prefix = ((unsigned)t1 << 11) | (unsigned)t2;
  for (int j = tid; j < 1024; j += 256) h3c[j] = 0u;
  __syncthreads();
  const size_t base = (size_t)b * A_N + (size_t)blockIdx.x * 4096;
  for (int i = 0; i < 16; ++i) {
    unsigned int bits = ceBits[base + i * 256 + tid];
    if ((bits >> 10) == prefix) atomicAdd(&h3c[bits & 1023], 1u);
  }
  __syncthreads();
  for (int j = tid; j < 1024; j += 256) {
    unsigned int cc = h3c[j];
    if (cc) atomicAdd(h3cnt + b * 1024 + j, cc);
  }
}

// --------------------------------------------------------------- final combine
__launch_bounds__(256)
__global__ void k_final(const unsigned int* __restrict__ h1cnt,
                        const double* __restrict__ h1sum,
                        const unsigned int* __restrict__ h2cnt,
                        const double* __restrict__ h2sum,
                        const unsigned int* __restrict__ h3cnt,
                        const unsigned int* __restrict__ numpos,
                        const double* __restrict__ lossL,
                        const double* __restrict__ lossCpos,
                        double* __restrict__ lossCneg,
                        unsigned int* __restrict__ ticket,
                        float* __restrict__ out)
{
  __shared__ unsigned int scanBuf[256];
  __shared__ int sT; __shared__ unsigned int sAb;
  __shared__ double lred[4];
  const int b = blockIdx.x;
  const int tid = threadIdx.x;
  const unsigned int P = numpos[b];
  const unsigned int k = min(3u * P, (unsigned)A_N - P);
  if (k > 0u) {
    findBin<8>(h1cnt + b * 2048, k, scanBuf, &sT, &sAb);
    const int t1 = sT; const unsigned int k1 = k - sAb;
    findBin<8>(h2cnt + b * 2048, k1, scanBuf, &sT, &sAb);
    const int t2 = sT; const unsigned int k2 = k1 - sAb;
    findBin<4>(h3cnt + b * 1024, k2, scanBuf, &sT, &sAb);
    const int t3 = sT; const unsigned int ab3 = sAb;
    double s = 0.0;
    for (int j = tid; j < 2048; j += 256) {
      if (j > t1) s += h1sum[b * 2048 + j];
      if (j > t2) s += h2sum[b * 2048 + j];
    }
    for (int j = tid; j < 1024; j += 256) {
      if (j > t3) {
        unsigned int cc = h3cnt[b * 1024 + j];
        if (cc) s += (double)cc * (double)__uint_as_float(
                     (((unsigned)t1 << 21) | ((unsigned)t2 << 10) | (unsigned)j));
      }
    }
    const int lane = tid & 63, wave = tid >> 6;
    for (int off = 32; off; off >>= 1) s += __shfl_down(s, off);
    if (lane == 0) lred[wave] = s;
    __syncthreads();
    if (tid == 0) {
      double tot = lred[0] + lred[1] + lred[2] + lred[3];
      tot += (double)(k2 - ab3) * (double)__uint_as_float(
                 (((unsigned)t1 << 21) | ((unsigned)t2 << 10) | (unsigned)t3));
      atomicAdd(lossCneg, tot);
    }
  }
  __threadfence();
  if (tid == 0) {
    unsigned int tk = atomicAdd(ticket, 1u);
    if (tk == B_N - 1) {
      double lcn = atomicAdd(lossCneg, 0.0);
      double ll = *lossL, lcp = *lossCpos;
      unsigned int tot = 0;
      #pragma unroll
      for (int i = 0; i < B_N; ++i) tot += numpos[i];
      double tn = (double)tot;
      out[0] = (float)(ll / tn);
      out[1] = (float)((lcp + lcn) / tn);
    }
  }
}

// -------------------------------------------------------------------- launcher
extern "C" void kernel_launch(void* const* d_in, const int* in_sizes, int n_in,
                              void* d_out, int out_size, void* d_ws, size_t ws_size,
                              hipStream_t stream)
{
  const float2* loc     = (const float2*)d_in[0];  // (B,A,2)
  const float2* confp   = (const float2*)d_in[1];  // (B,A,2)
  const float4* anchors = (const float4*)d_in[2];  // (A,4)
  const float*  targets = (const float*)d_in[3];   // (B,M,5)
  char* ws = (char*)d_ws;
  // zero-init region [0, 430144): scalars, bpi, hist counts, hist sums
  double* lossL  = (double*)(ws + 0);
  double* lossCp = (double*)(ws + 8);
  double* lossCn = (double*)(ws + 16);
  unsigned int* ticket = (unsigned int*)(ws + 24);
  unsigned int* numpos = (unsigned int*)(ws + 32);          // [8]
  unsigned long long* bpi = (unsigned long long*)(ws + 64); // [512]
  unsigned int* h1c = (unsigned int*)(ws + 4160);           // [8*2048]
  unsigned int* h2c = (unsigned int*)(ws + 69696);          // [8*2048]
  unsigned int* h3c = (unsigned int*)(ws + 135232);         // [8*1024]
  double* h1s = (double*)(ws + 168000);                     // [8*2048]
  double* h2s = (double*)(ws + 299072);                     // [8*2048]
  const size_t ZINIT = 430144;
  float4* tbox = (float4*)(ws + ZINIT);                     // [512]
  float2* tav  = (float2*)(ws + ZINIT + 8192);              // [512]
  float* bestOv = (float*)(ws + ZINIT + 12288);             // [B*A]
  int* bestIdx  = (int*)(ws + ZINIT + 12288 + 4194304);     // [B*A]
  unsigned int* ceBits = (unsigned int*)(ws + ZINIT + 12288 + 8388608); // [B*A]
  // total ws use ~12.4 MB

  hipMemsetAsync(d_ws, 0, ZINIT, stream);
  k_prep<<<2, 256, 0, stream>>>(targets, tbox, tav);
  k_match<<<dim3(64, 8), 256, 0, stream>>>(anchors, tbox, tav, bestOv, bestIdx, bpi);
  k_override<<<1, 64, 0, stream>>>(tav, bpi, bestOv, bestIdx);
  k_main<<<dim3(32, 8), 256, 0, stream>>>(loc, confp, anchors, tbox, tav, bestOv,
                                          bestIdx, ceBits, h1c, h1s, lossL, lossCp,
                                          numpos);
  k_sel2<<<dim3(32, 8), 256, 0, stream>>>(ceBits, h1c, h2c, h2s, numpos);
  k_sel3<<<dim3(32, 8), 256, 0, stream>>>(ceBits, h1c, h2c, h3c, numpos);
  k_final<<<8, 256, 0, stream>>>(h1c, h1s, h2c, h2s, h3c, numpos, lossL, lossCp,
                                 lossCn, ticket, (float*)d_out);
}

// Round 2
// 191.559 us; speedup vs baseline: 2.4525x; 2.4525x over previous
//
#include <hip/hip_runtime.h>
#include <cstdint>
#include <cstddef>

// CPDLoss (SSD MultiBox-style): B=8 batches, A=131072 anchors, M=64 truths.
// Pipeline: memset(ws) -> prep -> match -> override -> main -> sel2 -> sel3 -> final.
// R2: k_match restructured — anchors in registers, ONE u64-key butterfly per
// valid truth (was: per (anchor,truth)), invalid truths (wave-uniform) skipped.

#define A_N 131072
#define B_N 8
#define M_N 64
#define OVTH 0.5f
#define VAR0 0.1f

// ---------------------------------------------------------------- prep targets
__global__ void k_prep(const float* __restrict__ targets,
                       float4* __restrict__ tbox, float2* __restrict__ tav)
{
  int i = blockIdx.x * blockDim.x + threadIdx.x;
  if (i >= B_N * M_N) return;
  const float* t = targets + (size_t)i * 5;
  float x1 = t[0], y1 = t[1], x2 = t[2], y2 = t[3], lab = t[4];
  tbox[i] = make_float4(x1, y1, x2, y2);
  tav[i]  = make_float2((x2 - x1) * (y2 - y1), lab > 0.f ? 1.f : 0.f);
}

// ---------------------------------------------------------------- match kernel
// thread = 8 anchors (corners+area held in VGPRs). Outer loop m (64 truths):
//  - invalid truth (uniform): only the "-1 row" argmax bookkeeping, no IoU.
//  - valid truth: 8 IoU+div evals -> per-anchor best (bv,bm) and ONE packed
//    u64 key (q_bits<<32 | (0x7FFFFFFF - a)); one 6-step u64 butterfly per m;
//    wave lane0 -> LDS slot; block epilogue combines 4 waves -> global atomicMax.
// Tie semantics: q bits identical => larger inv = smaller anchor wins (= np
// first-max); per-anchor strict > keeps first m (= np argmax).
__launch_bounds__(256)
__global__ void k_match(const float4* __restrict__ anchors,
                        const float4* __restrict__ tbox,
                        const float2* __restrict__ tav,
                        float* __restrict__ bestOv,
                        int* __restrict__ bestIdx,
                        unsigned long long* __restrict__ bpi)
{
  __shared__ unsigned long long sKey[M_N][4];
  const int tid = threadIdx.x;
  const int wave = tid >> 6, lane = tid & 63;
  ((unsigned long long*)sKey)[tid] = 0ull;
  __syncthreads();
  const int b = blockIdx.y;
  const float4* tb = tbox + b * M_N;
  const float2* ta = tav + b * M_N;
  const int a0 = blockIdx.x * 2048 + tid;       // anchors a0 + i*256, i<8
  float ax1[8], ay1[8], ax2[8], ay2[8], sa[8];
  float bv[8]; int bm[8];
  #pragma unroll
  for (int i = 0; i < 8; ++i) {
    float4 an = anchors[a0 + i * 256];
    ax1[i] = an.x - an.z * 0.5f; ay1[i] = an.y - an.w * 0.5f;
    ax2[i] = an.x + an.z * 0.5f; ay2[i] = an.y + an.w * 0.5f;
    sa[i] = (ax2[i] - ax1[i]) * (ay2[i] - ay1[i]);
    bv[i] = -2.0f; bm[i] = 0;
  }
  for (int m = 0; m < M_N; ++m) {
    float2 av = ta[m];
    if (av.y > 0.f) {
      float4 t = tb[m];
      unsigned long long key = 0ull;
      #pragma unroll
      for (int i = 0; i < 8; ++i) {
        float wx = fminf(ax2[i], t.z) - fmaxf(ax1[i], t.x);
        float wy = fminf(ay2[i], t.w) - fmaxf(ay1[i], t.y);
        float inter = fmaxf(wx, 0.f) * fmaxf(wy, 0.f);
        float uni = (sa[i] + av.x) - inter;
        float q = inter / uni;                  // exact IEEE div: np ordering
        if (q > bv[i]) { bv[i] = q; bm[i] = m; }
        unsigned long long k2 =
            ((unsigned long long)__float_as_uint(q) << 32) |
            (unsigned long long)(0x7FFFFFFFu - (unsigned)(a0 + i * 256));
        key = (k2 > key) ? k2 : key;
      }
      #pragma unroll
      for (int off = 32; off; off >>= 1) {
        unsigned long long o = __shfl_xor(key, off);
        key = (o > key) ? o : key;
      }
      if (lane == 0) sKey[m][wave] = key;
    } else {
      // masked row: value -1 for every anchor; only wins while bv == -2
      #pragma unroll
      for (int i = 0; i < 8; ++i)
        if (bv[i] < -1.0f) { bv[i] = -1.0f; bm[i] = m; }
    }
  }
  #pragma unroll
  for (int i = 0; i < 8; ++i) {
    bestOv[(size_t)b * A_N + a0 + i * 256] = bv[i];
    bestIdx[(size_t)b * A_N + a0 + i * 256] = bm[i];
  }
  __syncthreads();
  if (tid < M_N) {
    unsigned long long k0 = sKey[tid][0];
    #pragma unroll
    for (int w = 1; w < 4; ++w) {
      unsigned long long k2 = sKey[tid][w];
      k0 = (k2 > k0) ? k2 : k0;
    }
    if (k0) atomicMax(bpi + b * M_N + tid, k0);
  }
}

// ------------------------------------------------------------- forced override
// numpy scatter semantics: sequential ascending m, last write wins.
__global__ void k_override(const float2* __restrict__ tav,
                           const unsigned long long* __restrict__ bpi,
                           float* __restrict__ bestOv,
                           int* __restrict__ bestIdx)
{
  int b = threadIdx.x;
  if (b >= B_N) return;
  for (int m = 0; m < M_N; ++m) {
    if (tav[b * M_N + m].y > 0.f) {
      unsigned long long key = bpi[b * M_N + m];
      unsigned int a = 0x7FFFFFFFu - (unsigned int)(key & 0xFFFFFFFFull);
      bestOv[(size_t)b * A_N + a] = 2.0f;
      bestIdx[(size_t)b * A_N + a] = m;
    }
  }
}

// ------------------------------------------------------------------- main pass
__launch_bounds__(256)
__global__ void k_main(const float2* __restrict__ loc_pred,
                       const float2* __restrict__ conf_pred,
                       const float4* __restrict__ anchors,
                       const float4* __restrict__ tbox,
                       const float2* __restrict__ tav,
                       const float* __restrict__ bestOv,
                       const int* __restrict__ bestIdx,
                       unsigned int* __restrict__ ceBits,
                       unsigned int* __restrict__ h1cnt,
                       double* __restrict__ h1sum,
                       double* __restrict__ lossL,
                       double* __restrict__ lossCpos,
                       unsigned int* __restrict__ numpos)
{
  __shared__ unsigned int hc[2048];
  __shared__ float hs[2048];
  __shared__ double rL[4], rC[4];
  __shared__ unsigned int rN[4];
  const int tid = threadIdx.x;
  for (int j = tid; j < 2048; j += 256) { hc[j] = 0u; hs[j] = 0.f; }
  __syncthreads();
  const int b = blockIdx.y;
  const size_t gbase = (size_t)b * A_N + (size_t)blockIdx.x * 4096;
  double lL = 0.0, lC = 0.0;
  unsigned int npc = 0;
  for (int i = 0; i < 16; ++i) {
    const size_t g = gbase + i * 256 + tid;
    const int a = (int)(g - (size_t)b * A_N);
    float ov = bestOv[g];
    int idx = bestIdx[g];
    float2 av = tav[b * M_N + idx];
    int conf = (ov < OVTH) ? 0 : (av.y > 0.f ? 1 : 0);
    float2 cp = conf_pred[g];
    float mx = fmaxf(cp.x, cp.y), mn = fminf(cp.x, cp.y);
    float ce = (mx + log1pf(expf(mn - mx))) - (conf ? cp.y : cp.x);
    unsigned int bits = 0u;
    float hval = 0.f;
    if (conf) {
      npc++; lC += (double)ce;
      float4 t = tbox[b * M_N + idx];
      float4 an = anchors[a];
      float gx = ((t.x + t.z) * 0.5f - an.x) / (VAR0 * an.z);
      float gy = ((t.y + t.w) * 0.5f - an.y) / (VAR0 * an.w);
      float2 lp = loc_pred[g];
      float dx = fabsf(lp.x - gx), dy = fabsf(lp.y - gy);
      lL += (double)((dx < 1.f ? 0.5f * dx * dx : dx - 0.5f) +
                     (dy < 1.f ? 0.5f * dy * dy : dy - 0.5f));
    } else {
      bits = __float_as_uint(ce);   // ce > 0 -> monotone bits
      hval = ce;
    }
    ceBits[g] = bits;
    atomicAdd(&hc[bits >> 21], 1u);
    atomicAdd(&hs[bits >> 21], hval);
  }
  __syncthreads();
  for (int j = tid; j < 2048; j += 256) {
    unsigned int c = hc[j];
    if (c) {
      atomicAdd(h1cnt + b * 2048 + j, c);
      atomicAdd(h1sum + b * 2048 + j, (double)hs[j]);
    }
  }
  const int lane = tid & 63, wave = tid >> 6;
  for (int off = 32; off; off >>= 1) {
    lL += __shfl_down(lL, off);
    lC += __shfl_down(lC, off);
    npc += __shfl_down(npc, off);
  }
  if (lane == 0) { rL[wave] = lL; rC[wave] = lC; rN[wave] = npc; }
  __syncthreads();
  if (tid == 0) {
    double aL = 0, aC = 0; unsigned int n = 0;
    for (int w = 0; w < 4; ++w) { aL += rL[w]; aC += rC[w]; n += rN[w]; }
    if (aL != 0.0) atomicAdd(lossL, aL);
    if (aC != 0.0) atomicAdd(lossCpos, aC);
    if (n) atomicAdd(numpos + b, n);
  }
}

// ------------------------------------------------- radix-select helper (block)
// Finds bin t containing the k-th largest; outAb = count of entries in bins > t.
template <int PER>
__device__ void findBin(const unsigned int* __restrict__ h, unsigned int k,
                        unsigned int* scanBuf, int* outT, unsigned int* outAb)
{
  const int tid = threadIdx.x;
  unsigned int c[PER];
  unsigned int ps = 0;
  #pragma unroll
  for (int j = 0; j < PER; ++j) { c[j] = h[tid * PER + j]; ps += c[j]; }
  scanBuf[tid] = ps;
  __syncthreads();
  unsigned int v = ps;
  for (int off = 1; off < 256; off <<= 1) {
    unsigned int u = (tid + off < 256) ? scanBuf[tid + off] : 0u;
    __syncthreads();
    v += u;
    scanBuf[tid] = v;
    __syncthreads();
  }
  unsigned int above = v - ps;  // entries in chunks strictly above this thread's
  #pragma unroll
  for (int j = PER - 1; j >= 0; --j) {
    unsigned int cj = c[j];
    if (above < k && above + cj >= k) { *outT = tid * PER + j; *outAb = above; }
    above += cj;
  }
  __syncthreads();
}

// ----------------------------------------------------------- level-2 histogram
__launch_bounds__(256)
__global__ void k_sel2(const unsigned int* __restrict__ ceBits,
                       const unsigned int* __restrict__ h1cnt,
                       unsigned int* __restrict__ h2cnt,
                       double* __restrict__ h2sum,
                       const unsigned int* __restrict__ numpos)
{
  __shared__ unsigned int scanBuf[256];
  __shared__ int sT; __shared__ unsigned int sAb;
  __shared__ unsigned int h2c[2048];
  __shared__ float h2s[2048];
  const int b = blockIdx.y;
  const unsigned int P = numpos[b];
  const unsigned int k = min(3u * P, (unsigned)A_N - P);
  if (k == 0u) return;
  const int tid = threadIdx.x;
  findBin<8>(h1cnt + b * 2048, k, scanBuf, &sT, &sAb);
  const int t1 = sT;
  for (int j = tid; j < 2048; j += 256) { h2c[j] = 0u; h2s[j] = 0.f; }
  __syncthreads();
  const size_t base = (size_t)b * A_N + (size_t)blockIdx.x * 4096;
  for (int i = 0; i < 16; ++i) {
    unsigned int bits = ceBits[base + i * 256 + tid];
    if ((int)(bits >> 21) == t1) {
      int bin = (bits >> 10) & 2047;
      atomicAdd(&h2c[bin], 1u);
      atomicAdd(&h2s[bin], __uint_as_float(bits));
    }
  }
  __syncthreads();
  for (int j = tid; j < 2048; j += 256) {
    unsigned int cc = h2c[j];
    if (cc) {
      atomicAdd(h2cnt + b * 2048 + j, cc);
      atomicAdd(h2sum + b * 2048 + j, (double)h2s[j]);
    }
  }
}

// ----------------------------------------------------------- level-3 histogram
__launch_bounds__(256)
__global__ void k_sel3(const unsigned int* __restrict__ ceBits,
                       const unsigned int* __restrict__ h1cnt,
                       const unsigned int* __restrict__ h2cnt,
                       unsigned int* __restrict__ h3cnt,
                       const unsigned int* __restrict__ numpos)
{
  __shared__ unsigned int scanBuf[256];
  __shared__ int sT; __shared__ unsigned int sAb;
  __shared__ unsigned int h3c[1024];
  const int b = blockIdx.y;
  const unsigned int P = numpos[b];
  const unsigned int k = min(3u * P, (unsigned)A_N - P);
  if (k == 0u) return;
  const int tid = threadIdx.x;
  findBin<8>(h1cnt + b * 2048, k, scanBuf, &sT, &sAb);
  const int t1 = sT; const unsigned int k1 = k - sAb;
  findBin<8>(h2cnt + b * 2048, k1, scanBuf, &sT, &sAb);
  const int t2 = sT;
  const unsigned int prefix = ((unsigned)t1 << 11) | (unsigned)t2;
  for (int j = tid; j < 1024; j += 256) h3c[j] = 0u;
  __syncthreads();
  const size_t base = (size_t)b * A_N + (size_t)blockIdx.x * 4096;
  for (int i = 0; i < 16; ++i) {
    unsigned int bits = ceBits[base + i * 256 + tid];
    if ((bits >> 10) == prefix) atomicAdd(&h3c[bits & 1023], 1u);
  }
  __syncthreads();
  for (int j = tid; j < 1024; j += 256) {
    unsigned int cc = h3c[j];
    if (cc) atomicAdd(h3cnt + b * 1024 + j, cc);
  }
}

// --------------------------------------------------------------- final combine
__launch_bounds__(256)
__global__ void k_final(const unsigned int* __restrict__ h1cnt,
                        const double* __restrict__ h1sum,
                        const unsigned int* __restrict__ h2cnt,
                        const double* __restrict__ h2sum,
                        const unsigned int* __restrict__ h3cnt,
                        const unsigned int* __restrict__ numpos,
                        const double* __restrict__ lossL,
                        const double* __restrict__ lossCpos,
                        double* __restrict__ lossCneg,
                        unsigned int* __restrict__ ticket,
                        float* __restrict__ out)
{
  __shared__ unsigned int scanBuf[256];
  __shared__ int sT; __shared__ unsigned int sAb;
  __shared__ double lred[4];
  const int b = blockIdx.x;
  const int tid = threadIdx.x;
  const unsigned int P = numpos[b];
  const unsigned int k = min(3u * P, (unsigned)A_N - P);
  if (k > 0u) {
    findBin<8>(h1cnt + b * 2048, k, scanBuf, &sT, &sAb);
    const int t1 = sT; const unsigned int k1 = k - sAb;
    findBin<8>(h2cnt + b * 2048, k1, scanBuf, &sT, &sAb);
    const int t2 = sT; const unsigned int k2 = k1 - sAb;
    findBin<4>(h3cnt + b * 1024, k2, scanBuf, &sT, &sAb);
    const int t3 = sT; const unsigned int ab3 = sAb;
    double s = 0.0;
    for (int j = tid; j < 2048; j += 256) {
      if (j > t1) s += h1sum[b * 2048 + j];
      if (j > t2) s += h2sum[b * 2048 + j];
    }
    for (int j = tid; j < 1024; j += 256) {
      if (j > t3) {
        unsigned int cc = h3cnt[b * 1024 + j];
        if (cc) s += (double)cc * (double)__uint_as_float(
                     (((unsigned)t1 << 21) | ((unsigned)t2 << 10) | (unsigned)j));
      }
    }
    const int lane = tid & 63, wave = tid >> 6;
    for (int off = 32; off; off >>= 1) s += __shfl_down(s, off);
    if (lane == 0) lred[wave] = s;
    __syncthreads();
    if (tid == 0) {
      double tot = lred[0] + lred[1] + lred[2] + lred[3];
      tot += (double)(k2 - ab3) * (double)__uint_as_float(
                 (((unsigned)t1 << 21) | ((unsigned)t2 << 10) | (unsigned)t3));
      atomicAdd(lossCneg, tot);
    }
  }
  __threadfence();
  if (tid == 0) {
    unsigned int tk = atomicAdd(ticket, 1u);
    if (tk == B_N - 1) {
      double lcn = atomicAdd(lossCneg, 0.0);
      double ll = *lossL, lcp = *lossCpos;
      unsigned int tot = 0;
      #pragma unroll
      for (int i = 0; i < B_N; ++i) tot += numpos[i];
      double tn = (double)tot;
      out[0] = (float)(ll / tn);
      out[1] = (float)((lcp + lcn) / tn);
    }
  }
}

// -------------------------------------------------------------------- launcher
extern "C" void kernel_launch(void* const* d_in, const int* in_sizes, int n_in,
                              void* d_out, int out_size, void* d_ws, size_t ws_size,
                              hipStream_t stream)
{
  const float2* loc     = (const float2*)d_in[0];  // (B,A,2)
  const float2* confp   = (const float2*)d_in[1];  // (B,A,2)
  const float4* anchors = (const float4*)d_in[2];  // (A,4)
  const float*  targets = (const float*)d_in[3];   // (B,M,5)
  char* ws = (char*)d_ws;
  // zero-init region [0, 430144): scalars, bpi, hist counts, hist sums
  double* lossL  = (double*)(ws + 0);
  double* lossCp = (double*)(ws + 8);
  double* lossCn = (double*)(ws + 16);
  unsigned int* ticket = (unsigned int*)(ws + 24);
  unsigned int* numpos = (unsigned int*)(ws + 32);          // [8]
  unsigned long long* bpi = (unsigned long long*)(ws + 64); // [512]
  unsigned int* h1c = (unsigned int*)(ws + 4160);           // [8*2048]
  unsigned int* h2c = (unsigned int*)(ws + 69696);          // [8*2048]
  unsigned int* h3c = (unsigned int*)(ws + 135232);         // [8*1024]
  double* h1s = (double*)(ws + 168000);                     // [8*2048]
  double* h2s = (double*)(ws + 299072);                     // [8*2048]
  const size_t ZINIT = 430144;
  float4* tbox = (float4*)(ws + ZINIT);                     // [512]
  float2* tav  = (float2*)(ws + ZINIT + 8192);              // [512]
  float* bestOv = (float*)(ws + ZINIT + 12288);             // [B*A]
  int* bestIdx  = (int*)(ws + ZINIT + 12288 + 4194304);     // [B*A]
  unsigned int* ceBits = (unsigned int*)(ws + ZINIT + 12288 + 8388608); // [B*A]
  // total ws use ~12.4 MB

  hipMemsetAsync(d_ws, 0, ZINIT, stream);
  k_prep<<<2, 256, 0, stream>>>(targets, tbox, tav);
  k_match<<<dim3(64, 8), 256, 0, stream>>>(anchors, tbox, tav, bestOv, bestIdx, bpi);
  k_override<<<1, 64, 0, stream>>>(tav, bpi, bestOv, bestIdx);
  k_main<<<dim3(32, 8), 256, 0, stream>>>(loc, confp, anchors, tbox, tav, bestOv,
                                          bestIdx, ceBits, h1c, h1s, lossL, lossCp,
                                          numpos);
  k_sel2<<<dim3(32, 8), 256, 0, stream>>>(ceBits, h1c, h2c, h2s, numpos);
  k_sel3<<<dim3(32, 8), 256, 0, stream>>>(ceBits, h1c, h2c, h3c, numpos);
  k_final<<<8, 256, 0, stream>>>(h1c, h1s, h2c, h2s, h3c, numpos, lossL, lossCp,
                                 lossCn, ticket, (float*)d_out);
}